// Round 10
// baseline (252.255 us; speedup 1.0000x reference)
//
#include <hip/hip_runtime.h>
#include <hip/hip_bf16.h>
#include <stdint.h>

#define EPS 1e-5f
#define NOUT 2338   // 2048+256+32+1+1 output cols per batch row

typedef __bf16 bf16x8 __attribute__((ext_vector_type(8)));
typedef float f32x4 __attribute__((ext_vector_type(4)));
typedef unsigned short u16;

__device__ __forceinline__ u16 f2bf_bits(float f) {
  uint32_t u = __builtin_bit_cast(uint32_t, f);
  u += 0x7FFFu + ((u >> 16) & 1u);   // RNE
  return (u16)(u >> 16);
}

__device__ __forceinline__ uint32_t pack2(float lo, float hi) {
  return (uint32_t)f2bf_bits(lo) | ((uint32_t)f2bf_bits(hi) << 16);
}

// ---------------- kernel 0: x [256][3008] f32 -> bf16, packed in MFMA B-frag tile order
// XBp[ks][kb][m][e] : ks in [0,94), kb in [0,4), m in [0,256), e in [0,8)
__global__ __launch_bounds__(256) void cvt_pack_kernel(const float* __restrict__ x,
                                                       u16* __restrict__ xbp) {
  const int i = blockIdx.x * 256 + threadIdx.x;   // 96256 total
  const int ks = i >> 10;
  const int rem = i & 1023;
  const int kb = rem >> 8;
  const int m = rem & 255;
  const f32x4* src = (const f32x4*)(x + (size_t)m * 3008 + ks * 32 + kb * 8);
  f32x4 a = src[0], b = src[1];
  uint4 o;
  o.x = pack2(a.x, a.y);
  o.y = pack2(a.z, a.w);
  o.z = pack2(b.x, b.y);
  o.w = pack2(b.z, b.w);
  ((uint4*)xbp)[i] = o;
}

// ---------------- kernel 1: leaf GEMM — NO LDS, NO BARRIERS.
// C [20480 x 256] = W[20480 x 3008] * X^T.  16x16x32 bf16 MFMA.
// block = 256 thr (4 waves), 64 rows x 256 m. Wave w: row-group rg=w>>1 (32 rows,
// 2 A-frags), m-half mh=w&1 (8 m-tiles). Each wave = independent 3-deep pipeline:
// B-frags loaded straight from L2-resident packed X into VGPRs; counted vmcnt(24).
__global__ __launch_bounds__(256, 2) void gemm_leaf(const float* __restrict__ W,
                                                    const float* __restrict__ gb,
                                                    const u16* __restrict__ XBp,
                                                    float* __restrict__ hout) {
  const int tid = threadIdx.x;
  const int w = tid >> 6;
  const int lane = tid & 63;
  const int rg = w >> 1;          // row-group 0..1 (32 rows each)
  const int mh = w & 1;           // m-half 0..1
  const int lquad = lane >> 4;    // k-group 0..3
  const int lmod = lane & 15;
  const int n0 = blockIdx.x * 64;
  const int r0 = n0 + rg * 32;

  f32x4 acc[2][8];
#pragma unroll
  for (int rt = 0; rt < 2; ++rt)
#pragma unroll
    for (int j = 0; j < 8; ++j) acc[rt][j] = (f32x4){0.f, 0.f, 0.f, 0.f};

  const float* wp0 = W + (size_t)(r0 + lmod) * 3008 + lquad * 8;
  const float* wp1 = W + (size_t)(r0 + 16 + lmod) * 3008 + lquad * 8;
  const u16* xb = XBp + (size_t)lquad * 2048 + mh * 1024 + lmod * 8;

  bf16x8 B[3][8];    // 3-deep B-fragment pipeline (static indices only)
  f32x4 Wr[3][4];    // 3-deep W fp32 pipeline: [rt0 lo, rt0 hi, rt1 lo, rt1 hi]

#define LOADB(t, ph)                                                                    \
  {                                                                                     \
    _Pragma("unroll")                                                                   \
    for (int j = 0; j < 8; ++j)                                                         \
      B[ph][j] = *(const bf16x8*)(xb + (size_t)(t) * 8192 + j * 128);                   \
  }

#define LOADW(t, ph)                                                                    \
  {                                                                                     \
    const f32x4* a0 = (const f32x4*)(wp0 + (size_t)(t) * 32);                           \
    Wr[ph][0] = __builtin_nontemporal_load(a0);                                         \
    Wr[ph][1] = __builtin_nontemporal_load(a0 + 1);                                     \
    const f32x4* a1 = (const f32x4*)(wp1 + (size_t)(t) * 32);                           \
    Wr[ph][2] = __builtin_nontemporal_load(a1);                                         \
    Wr[ph][3] = __builtin_nontemporal_load(a1 + 1);                                     \
  }

  // ITER: issue (t+2) loads early, wait for (t)'s data, compute 16 MFMA.
  // vmcnt counting (issue order pinned by sched_barrier(0)):
  //   outstanding after issue at iter t = B(t+1)8+W(t+1)4+B(t+2)8+W(t+2)4 = 24.
#define ITER(t, ph, phn, VM, ISSUE)                                                     \
  {                                                                                     \
    if (ISSUE) {                                                                        \
      LOADB((t) + 2, phn);                                                              \
      __builtin_amdgcn_sched_barrier(0);                                                \
      LOADW((t) + 2, phn);                                                              \
      __builtin_amdgcn_sched_barrier(0);                                                \
    }                                                                                   \
    asm volatile("s_waitcnt vmcnt(" #VM ")" ::: "memory");                              \
    __builtin_amdgcn_sched_barrier(0);                                                  \
    union { u16 u[8]; bf16x8 v; } af0, af1;                                             \
    af0.u[0] = f2bf_bits(Wr[ph][0].x); af0.u[1] = f2bf_bits(Wr[ph][0].y);               \
    af0.u[2] = f2bf_bits(Wr[ph][0].z); af0.u[3] = f2bf_bits(Wr[ph][0].w);               \
    af0.u[4] = f2bf_bits(Wr[ph][1].x); af0.u[5] = f2bf_bits(Wr[ph][1].y);               \
    af0.u[6] = f2bf_bits(Wr[ph][1].z); af0.u[7] = f2bf_bits(Wr[ph][1].w);               \
    af1.u[0] = f2bf_bits(Wr[ph][2].x); af1.u[1] = f2bf_bits(Wr[ph][2].y);               \
    af1.u[2] = f2bf_bits(Wr[ph][2].z); af1.u[3] = f2bf_bits(Wr[ph][2].w);               \
    af1.u[4] = f2bf_bits(Wr[ph][3].x); af1.u[5] = f2bf_bits(Wr[ph][3].y);               \
    af1.u[6] = f2bf_bits(Wr[ph][3].z); af1.u[7] = f2bf_bits(Wr[ph][3].w);               \
    _Pragma("unroll")                                                                   \
    for (int j = 0; j < 8; ++j) {                                                       \
      acc[0][j] = __builtin_amdgcn_mfma_f32_16x16x32_bf16(af0.v, B[ph][j], acc[0][j],   \
                                                          0, 0, 0);                     \
      acc[1][j] = __builtin_amdgcn_mfma_f32_16x16x32_bf16(af1.v, B[ph][j], acc[1][j],   \
                                                          0, 0, 0);                     \
    }                                                                                   \
  }

  // prologue: B(0),W(0),B(1),W(1), order pinned
  LOADB(0, 0);
  __builtin_amdgcn_sched_barrier(0);
  LOADW(0, 0);
  __builtin_amdgcn_sched_barrier(0);
  LOADB(1, 1);
  __builtin_amdgcn_sched_barrier(0);
  LOADW(1, 1);
  __builtin_amdgcn_sched_barrier(0);

  // 94 k-steps: t = 0..89 in unroll-by-3 loop, then 90,91 (issue), 92,93 (drain)
  for (int t = 0; t < 90; t += 3) {
    ITER(t + 0, 0, 2, 24, true);
    ITER(t + 1, 1, 0, 24, true);
    ITER(t + 2, 2, 1, 24, true);
  }
  ITER(90, 0, 2, 24, true);
  ITER(91, 1, 0, 24, true);
  ITER(92, 2, 2, 12, false);
  ITER(93, 0, 0, 0, false);

#undef ITER
#undef LOADW
#undef LOADB

  // store: D row = r0 + rt*16 + lquad*4 + r2, col = (mh*8+j)*16 + lmod
#pragma unroll
  for (int rt = 0; rt < 2; ++rt) {
    const int rr = r0 + rt * 16 + lquad * 4;
    float gb4[4];
#pragma unroll
    for (int r2 = 0; r2 < 4; ++r2) gb4[r2] = gb[rr + r2];
#pragma unroll
    for (int j = 0; j < 8; ++j) {
      const int col = (mh * 8 + j) * 16 + lmod;
#pragma unroll
      for (int r2 = 0; r2 < 4; ++r2) {
        hout[(size_t)(rr + r2) * 256 + col] = acc[rt][j][r2] + gb4[r2];
      }
    }
  }
}

// ---------------- per-level kernel (levels 0..2): one term per block, batch = 256 threads
__global__ __launch_bounds__(256) void level_kernel(
    const float* __restrict__ yin, const float* __restrict__ w,
    const float* __restrict__ bia, const float* __restrict__ gam,
    const float* __restrict__ bet, const float* __restrict__ p,
    const float* __restrict__ q, const float* __restrict__ r,
    const float* __restrict__ s, float* __restrict__ yout,
    float* __restrict__ out, int inl, int off) {
  const int t = blockIdx.x;
  const int b = threadIdx.x;
  __shared__ float wls[6 * 48];
  __shared__ float part[4][12];
  __shared__ float stats[12];  // mean[6], rstd[6]
  const float* wt = w + (size_t)t * 6 * inl;
  for (int i = b; i < 6 * inl; i += 256) wls[i] = wt[i];
  __syncthreads();

  float z[6];
#pragma unroll
  for (int h = 0; h < 6; ++h) z[h] = bia[t * 6 + h];
  const float* yp = yin + (size_t)t * inl * 256 + b;
  for (int i = 0; i < inl; ++i) {
    float v = yp[(size_t)i * 256];
#pragma unroll
    for (int h = 0; h < 6; ++h) z[h] = fmaf(v, wls[h * inl + i], z[h]);
  }
#pragma unroll
  for (int h = 0; h < 6; ++h) z[h] = tanhf(z[h]);

  float sm[6], sq[6];
#pragma unroll
  for (int h = 0; h < 6; ++h) { sm[h] = z[h]; sq[h] = z[h] * z[h]; }
#pragma unroll
  for (int o = 32; o > 0; o >>= 1) {
#pragma unroll
    for (int h = 0; h < 6; ++h) {
      sm[h] += __shfl_down(sm[h], o);
      sq[h] += __shfl_down(sq[h], o);
    }
  }
  const int lane = b & 63, wvi = b >> 6;
  if (lane == 0) {
#pragma unroll
    for (int h = 0; h < 6; ++h) { part[wvi][h] = sm[h]; part[wvi][6 + h] = sq[h]; }
  }
  __syncthreads();
  if (b < 6) {
    float msum = part[0][b] + part[1][b] + part[2][b] + part[3][b];
    float qsum = part[0][6 + b] + part[1][6 + b] + part[2][6 + b] + part[3][6 + b];
    float m = msum * (1.f / 256.f);
    float var = qsum * (1.f / 256.f) - m * m;
    stats[b] = m;
    stats[6 + b] = rsqrtf(var + EPS);
  }
  __syncthreads();

  float a = q[t];
#pragma unroll
  for (int h = 0; h < 6; ++h) {
    float yy = (z[h] - stats[h]) * stats[6 + h] * gam[t * 6 + h] + bet[t * 6 + h];
    yout[((size_t)t * 6 + h) * 256 + b] = yy;
    a = fmaf(yy, p[t * 6 + h], a);
  }
  out[(size_t)b * NOUT + off + t] = tanhf(a) * r[t] + s[t];
}

// ---------------- merged level-3 (inl=192, 1 term) + final head; single block
__global__ __launch_bounds__(256) void level3_final_kernel(
    const float* __restrict__ y2,
    const float* __restrict__ w3, const float* __restrict__ b3,
    const float* __restrict__ g3, const float* __restrict__ e3,
    const float* __restrict__ p3, const float* __restrict__ q3,
    const float* __restrict__ r3, const float* __restrict__ s3,
    const float* __restrict__ fw, const float* __restrict__ fb,
    const float* __restrict__ fg, const float* __restrict__ fe,
    const float* __restrict__ pw, const float* __restrict__ pb,
    const float* __restrict__ rw, const float* __restrict__ rb,
    float* __restrict__ out) {
  const int b = threadIdx.x;
  __shared__ float wls[6 * 192];
  __shared__ float part[4][24];
  __shared__ float stats[24];
  for (int i = b; i < 6 * 192; i += 256) wls[i] = w3[i];
  __syncthreads();

  // ---- level 3 (t = 0), inl = 192 ----
  float z[6];
#pragma unroll
  for (int h = 0; h < 6; ++h) z[h] = b3[h];
  const float* yp = y2 + b;
  for (int i = 0; i < 192; ++i) {
    float v = yp[(size_t)i * 256];
#pragma unroll
    for (int h = 0; h < 6; ++h) z[h] = fmaf(v, wls[h * 192 + i], z[h]);
  }
#pragma unroll
  for (int h = 0; h < 6; ++h) z[h] = tanhf(z[h]);

  const int lane = b & 63, wvi = b >> 6;
  {
    float sm[6], sq[6];
#pragma unroll
    for (int h = 0; h < 6; ++h) { sm[h] = z[h]; sq[h] = z[h] * z[h]; }
#pragma unroll
    for (int o = 32; o > 0; o >>= 1) {
#pragma unroll
      for (int h = 0; h < 6; ++h) {
        sm[h] += __shfl_down(sm[h], o);
        sq[h] += __shfl_down(sq[h], o);
      }
    }
    if (lane == 0) {
#pragma unroll
      for (int h = 0; h < 6; ++h) { part[wvi][h] = sm[h]; part[wvi][6 + h] = sq[h]; }
    }
    __syncthreads();
    if (b < 6) {
      float msum = part[0][b] + part[1][b] + part[2][b] + part[3][b];
      float qsum = part[0][6 + b] + part[1][6 + b] + part[2][6 + b] + part[3][6 + b];
      float m = msum * (1.f / 256.f);
      float var = qsum * (1.f / 256.f) - m * m;
      stats[b] = m;
      stats[6 + b] = rsqrtf(var + EPS);
    }
    __syncthreads();
  }

  float yr[6];
  float a3 = q3[0];
#pragma unroll
  for (int h = 0; h < 6; ++h) {
    yr[h] = (z[h] - stats[h]) * stats[6 + h] * g3[h] + e3[h];
    a3 = fmaf(yr[h], p3[h], a3);
  }
  out[(size_t)b * NOUT + 2336] = tanhf(a3) * r3[0] + s3[0];
  __syncthreads();   // stats[] about to be reused

  // ---- final head ----
  float zf[12];
#pragma unroll
  for (int j = 0; j < 12; ++j) {
    float a = fb[j];
#pragma unroll
    for (int h = 0; h < 6; ++h) a = fmaf(yr[h], fw[j * 6 + h], a);
    zf[j] = tanhf(a);
  }
  {
    float sm[12], sq[12];
#pragma unroll
    for (int j = 0; j < 12; ++j) { sm[j] = zf[j]; sq[j] = zf[j] * zf[j]; }
#pragma unroll
    for (int o = 32; o > 0; o >>= 1) {
#pragma unroll
      for (int j = 0; j < 12; ++j) {
        sm[j] += __shfl_down(sm[j], o);
        sq[j] += __shfl_down(sq[j], o);
      }
    }
    if (lane == 0) {
#pragma unroll
      for (int j = 0; j < 12; ++j) { part[wvi][j] = sm[j]; part[wvi][12 + j] = sq[j]; }
    }
    __syncthreads();
    if (b < 12) {
      float msum = part[0][b] + part[1][b] + part[2][b] + part[3][b];
      float qsum = part[0][12 + b] + part[1][12 + b] + part[2][12 + b] + part[3][12 + b];
      float m = msum * (1.f / 256.f);
      float var = qsum * (1.f / 256.f) - m * m;
      stats[b] = m;
      stats[12 + b] = rsqrtf(var + EPS);
    }
    __syncthreads();
  }
  float a = pb[0];
#pragma unroll
  for (int j = 0; j < 12; ++j) {
    float of = (zf[j] - stats[j]) * stats[12 + j] * fg[j] + fe[j];
    a = fmaf(of, pw[j], a);
  }
  out[(size_t)b * NOUT + 2337] = tanhf(a) * rw[0] + rb[0];
}

extern "C" void kernel_launch(void* const* d_in, const int* in_sizes, int n_in,
                              void* d_out, int out_size, void* d_ws, size_t ws_size,
                              hipStream_t stream) {
  const float* x  = (const float*)d_in[0];
  const float* gW = (const float*)d_in[1];
  const float* gb = (const float*)d_in[2];
  float* out = (float*)d_out;

  char* wsb = (char*)d_ws;
  u16* XBp = (u16*)wsb;                              // 256*3008 bf16 (packed)
  float* h0 = (float*)(wsb + 1540096);               // [20480][256]
  float* y0 = h0 + (size_t)20480 * 256;              // [12288][256]
  float* y1 = y0 + (size_t)12288 * 256;              // [1536][256]
  float* y2 = y1 + (size_t)1536 * 256;               // [192][256]

  cvt_pack_kernel<<<dim3(376), dim3(256), 0, stream>>>(x, XBp);
  gemm_leaf<<<dim3(320), dim3(256), 0, stream>>>(gW, gb, XBp, h0);

#define LV(base, yin, yout, inl, off, grid)                                           \
  level_kernel<<<dim3(grid), dim3(256), 0, stream>>>(                                 \
      yin, (const float*)d_in[base], (const float*)d_in[base + 1],                    \
      (const float*)d_in[base + 2], (const float*)d_in[base + 3],                     \
      (const float*)d_in[base + 4], (const float*)d_in[base + 5],                     \
      (const float*)d_in[base + 6], (const float*)d_in[base + 7], yout, out, inl, off)

  LV(3,  h0, y0, 10,  0,    2048);
  LV(11, y0, y1, 48,  2048, 256);
  LV(19, y1, y2, 48,  2304, 32);
#undef LV

  level3_final_kernel<<<dim3(1), dim3(256), 0, stream>>>(
      y2,
      (const float*)d_in[27], (const float*)d_in[28], (const float*)d_in[29],
      (const float*)d_in[30], (const float*)d_in[31], (const float*)d_in[32],
      (const float*)d_in[33], (const float*)d_in[34],
      (const float*)d_in[35], (const float*)d_in[36], (const float*)d_in[37],
      (const float*)d_in[38], (const float*)d_in[39], (const float*)d_in[40],
      (const float*)d_in[41], (const float*)d_in[42], out);
}

// Round 11
// 186.004 us; speedup vs baseline: 1.3562x; 1.3562x over previous
//
#include <hip/hip_runtime.h>
#include <hip/hip_bf16.h>
#include <stdint.h>

#define EPS 1e-5f
#define NOUT 2338   // 2048+256+32+1+1 output cols per batch row

typedef __bf16 bf16x8 __attribute__((ext_vector_type(8)));
typedef float f32x4 __attribute__((ext_vector_type(4)));
typedef unsigned short u16;

__device__ __forceinline__ u16 f2bf_bits(float f) {
  uint32_t u = __builtin_bit_cast(uint32_t, f);
  u += 0x7FFFu + ((u >> 16) & 1u);   // RNE
  return (u16)(u >> 16);
}

__device__ __forceinline__ uint32_t pack2(float lo, float hi) {
  return (uint32_t)f2bf_bits(lo) | ((uint32_t)f2bf_bits(hi) << 16);
}

// ---------------- kernel 0: x [256][3008] f32 -> bf16, packed in MFMA B-frag tile order
// XBp[ks][kb][m][e] : ks in [0,94), kb in [0,4), m in [0,256), e in [0,8)
__global__ __launch_bounds__(256) void cvt_pack_kernel(const float* __restrict__ x,
                                                       u16* __restrict__ xbp) {
  const int i = blockIdx.x * 256 + threadIdx.x;   // 96256 total
  const int ks = i >> 10;
  const int rem = i & 1023;
  const int kb = rem >> 8;
  const int m = rem & 255;
  const f32x4* src = (const f32x4*)(x + (size_t)m * 3008 + ks * 32 + kb * 8);
  f32x4 a = src[0], b = src[1];
  uint4 o;
  o.x = pack2(a.x, a.y);
  o.y = pack2(a.z, a.w);
  o.z = pack2(b.x, b.y);
  o.w = pack2(b.z, b.w);
  ((uint4*)xbp)[i] = o;
}

// ---------------- kernel 1: leaf GEMM — ALL VMEM COALESCED; W through LDS.
// C [20480 x 256] = W[20480 x 3008] * X^T.  16x16x32 bf16 MFMA.
// block = 256 thr (4 waves), 32 rows x 256 m. Wave w: rg=w>>1 (16 rows), mh=w&1.
// 64-k supersteps (47 total). Per superstep: stage 32KB X (32 coalesced 1KB gll)
// + 8KB W slab (8 coalesced 1KB gll, XOR-swizzled via pre-swizzled global src),
// one __syncthreads, compute 16 MFMA/wave. W frags via ds_read (LDS pipe, not TA).
__global__ __launch_bounds__(256) void gemm_leaf(const float* __restrict__ W,
                                                 const float* __restrict__ gb,
                                                 const u16* __restrict__ XBp,
                                                 float* __restrict__ hout) {
  __shared__ __align__(16) u16 xl[2][16384];   // 2 x 32KB: [buf][st(2)][kb(4)][m(256)][e(8)]
  __shared__ __align__(16) float wl[2][2048];  // 2 x 8KB:  [buf][row(32)][64f] XOR-swizzled
  const int tid = threadIdx.x;
  const int w = tid >> 6;
  const int lane = tid & 63;
  const int rg = w >> 1;          // row-group 0..1
  const int mh = w & 1;           // m-half 0..1
  const int lquad = lane >> 4;    // k-group 0..3
  const int lmod = lane & 15;
  const int n0 = blockIdx.x * 32;

  f32x4 acc[8];
#pragma unroll
  for (int i = 0; i < 8; ++i) acc[i] = (f32x4){0.f, 0.f, 0.f, 0.f};

  // --- W stage source pointers (per lane, per q): coalesced 1KB instr = rows 4j..4j+3
  // LDS[row][b] will hold W[row][b ^ ((row&7)<<4)] -> read with same XOR.
  const int j0 = w * 2 + 0, j1 = w * 2 + 1;
  const int row0 = j0 * 4 + (lane >> 4);         // lane>>4 in 0..3
  const int row1 = j1 * 4 + (lane >> 4);
  const int so0 = (((lane & 15) * 16) ^ ((row0 & 7) << 4)) >> 2;  // float idx in row-slab
  const int so1 = (((lane & 15) * 16) ^ ((row1 & 7) << 4)) >> 2;
  const float* wsrc0 = W + (size_t)(n0 + row0) * 3008 + so0;
  const float* wsrc1 = W + (size_t)(n0 + row1) * 3008 + so1;

  const u16* xsrc = XBp + (size_t)(w * 8) * 512 + lane * 8;   // instr base, +p*512 per chunk

#define STAGE_X(s, buf)                                                                 \
  {                                                                                     \
    _Pragma("unroll")                                                                   \
    for (int p = 0; p < 8; ++p) {                                                       \
      const u16* src = xsrc + (size_t)(s) * 16384 + p * 512;                            \
      u16* dst = &xl[buf][(w * 8 + p) * 512];                                           \
      __builtin_amdgcn_global_load_lds((const __attribute__((address_space(1))) void*)src, \
                                       (__attribute__((address_space(3))) void*)dst,    \
                                       16, 0, 0);                                       \
    }                                                                                   \
  }

#define STAGE_W(s, buf)                                                                 \
  {                                                                                     \
    __builtin_amdgcn_global_load_lds(                                                   \
        (const __attribute__((address_space(1))) void*)(wsrc0 + (size_t)(s) * 64),      \
        (__attribute__((address_space(3))) void*)&wl[buf][j0 * 256], 16, 0, 0);         \
    __builtin_amdgcn_global_load_lds(                                                   \
        (const __attribute__((address_space(1))) void*)(wsrc1 + (size_t)(s) * 64),      \
        (__attribute__((address_space(3))) void*)&wl[buf][j1 * 256], 16, 0, 0);         \
  }

  // W-frag read offsets (float idx), st = step parity within superstep
  const int wrow = rg * 16 + lmod;
  const int wkey = (lmod & 7) << 4;   // byte XOR key
  const float* wbase;  // set per buf below

  STAGE_X(0, 0);
  STAGE_W(0, 0);

  for (int s = 0; s < 47; ++s) {
    const int buf = s & 1;
    __syncthreads();   // drains stage(s) (vmcnt0+lgkm0+barrier)
    if (s < 46) {
      STAGE_X(s + 1, buf ^ 1);
      STAGE_W(s + 1, buf ^ 1);
    }
    __builtin_amdgcn_sched_barrier(0);   // keep stage issues before compute

    wbase = &wl[buf][0];
    const u16* xb = &xl[buf][(size_t)lquad * 2048 + mh * 1024 + lmod * 8];
#pragma unroll
    for (int st = 0; st < 2; ++st) {
      const int f0 = st * 128 + lquad * 32;    // byte offset in row-slab
      const f32x4 wlo = *(const f32x4*)(wbase + wrow * 64 + (((f0) ^ wkey) >> 2));
      const f32x4 whi = *(const f32x4*)(wbase + wrow * 64 + (((f0 + 16) ^ wkey) >> 2));
      union { u16 u[8]; bf16x8 v; } af;
      af.u[0] = f2bf_bits(wlo.x); af.u[1] = f2bf_bits(wlo.y);
      af.u[2] = f2bf_bits(wlo.z); af.u[3] = f2bf_bits(wlo.w);
      af.u[4] = f2bf_bits(whi.x); af.u[5] = f2bf_bits(whi.y);
      af.u[6] = f2bf_bits(whi.z); af.u[7] = f2bf_bits(whi.w);
#pragma unroll
      for (int j = 0; j < 8; ++j) {
        const bf16x8 bfrag = *(const bf16x8*)(xb + st * 8192 + j * 128);
        acc[j] = __builtin_amdgcn_mfma_f32_16x16x32_bf16(af.v, bfrag, acc[j], 0, 0, 0);
      }
    }
  }

#undef STAGE_W
#undef STAGE_X

  // store: D row = n0 + rg*16 + lquad*4 + r2, col = (mh*8+j)*16 + lmod
  const int r0 = n0 + rg * 16 + lquad * 4;
  float gb4[4];
#pragma unroll
  for (int r2 = 0; r2 < 4; ++r2) gb4[r2] = gb[r0 + r2];
#pragma unroll
  for (int j = 0; j < 8; ++j) {
    const int col = (mh * 8 + j) * 16 + lmod;
#pragma unroll
    for (int r2 = 0; r2 < 4; ++r2) {
      hout[(size_t)(r0 + r2) * 256 + col] = acc[j][r2] + gb4[r2];
    }
  }
}

// ---------------- per-level kernel (levels 0..2): one term per block, batch = 256 threads
__global__ __launch_bounds__(256) void level_kernel(
    const float* __restrict__ yin, const float* __restrict__ w,
    const float* __restrict__ bia, const float* __restrict__ gam,
    const float* __restrict__ bet, const float* __restrict__ p,
    const float* __restrict__ q, const float* __restrict__ r,
    const float* __restrict__ s, float* __restrict__ yout,
    float* __restrict__ out, int inl, int off) {
  const int t = blockIdx.x;
  const int b = threadIdx.x;
  __shared__ float wls[6 * 48];
  __shared__ float part[4][12];
  __shared__ float stats[12];  // mean[6], rstd[6]
  const float* wt = w + (size_t)t * 6 * inl;
  for (int i = b; i < 6 * inl; i += 256) wls[i] = wt[i];
  __syncthreads();

  float z[6];
#pragma unroll
  for (int h = 0; h < 6; ++h) z[h] = bia[t * 6 + h];
  const float* yp = yin + (size_t)t * inl * 256 + b;
  for (int i = 0; i < inl; ++i) {
    float v = yp[(size_t)i * 256];
#pragma unroll
    for (int h = 0; h < 6; ++h) z[h] = fmaf(v, wls[h * inl + i], z[h]);
  }
#pragma unroll
  for (int h = 0; h < 6; ++h) z[h] = tanhf(z[h]);

  float sm[6], sq[6];
#pragma unroll
  for (int h = 0; h < 6; ++h) { sm[h] = z[h]; sq[h] = z[h] * z[h]; }
#pragma unroll
  for (int o = 32; o > 0; o >>= 1) {
#pragma unroll
    for (int h = 0; h < 6; ++h) {
      sm[h] += __shfl_down(sm[h], o);
      sq[h] += __shfl_down(sq[h], o);
    }
  }
  const int lane = b & 63, wvi = b >> 6;
  if (lane == 0) {
#pragma unroll
    for (int h = 0; h < 6; ++h) { part[wvi][h] = sm[h]; part[wvi][6 + h] = sq[h]; }
  }
  __syncthreads();
  if (b < 6) {
    float msum = part[0][b] + part[1][b] + part[2][b] + part[3][b];
    float qsum = part[0][6 + b] + part[1][6 + b] + part[2][6 + b] + part[3][6 + b];
    float m = msum * (1.f / 256.f);
    float var = qsum * (1.f / 256.f) - m * m;
    stats[b] = m;
    stats[6 + b] = rsqrtf(var + EPS);
  }
  __syncthreads();

  float a = q[t];
#pragma unroll
  for (int h = 0; h < 6; ++h) {
    float yy = (z[h] - stats[h]) * stats[6 + h] * gam[t * 6 + h] + bet[t * 6 + h];
    yout[((size_t)t * 6 + h) * 256 + b] = yy;
    a = fmaf(yy, p[t * 6 + h], a);
  }
  out[(size_t)b * NOUT + off + t] = tanhf(a) * r[t] + s[t];
}

// ---------------- merged level-3 (inl=192, 1 term) + final head; single block
__global__ __launch_bounds__(256) void level3_final_kernel(
    const float* __restrict__ y2,
    const float* __restrict__ w3, const float* __restrict__ b3,
    const float* __restrict__ g3, const float* __restrict__ e3,
    const float* __restrict__ p3, const float* __restrict__ q3,
    const float* __restrict__ r3, const float* __restrict__ s3,
    const float* __restrict__ fw, const float* __restrict__ fb,
    const float* __restrict__ fg, const float* __restrict__ fe,
    const float* __restrict__ pw, const float* __restrict__ pb,
    const float* __restrict__ rw, const float* __restrict__ rb,
    float* __restrict__ out) {
  const int b = threadIdx.x;
  __shared__ float wls[6 * 192];
  __shared__ float part[4][24];
  __shared__ float stats[24];
  for (int i = b; i < 6 * 192; i += 256) wls[i] = w3[i];
  __syncthreads();

  // ---- level 3 (t = 0), inl = 192 ----
  float z[6];
#pragma unroll
  for (int h = 0; h < 6; ++h) z[h] = b3[h];
  const float* yp = y2 + b;
  for (int i = 0; i < 192; ++i) {
    float v = yp[(size_t)i * 256];
#pragma unroll
    for (int h = 0; h < 6; ++h) z[h] = fmaf(v, wls[h * 192 + i], z[h]);
  }
#pragma unroll
  for (int h = 0; h < 6; ++h) z[h] = tanhf(z[h]);

  const int lane = b & 63, wvi = b >> 6;
  {
    float sm[6], sq[6];
#pragma unroll
    for (int h = 0; h < 6; ++h) { sm[h] = z[h]; sq[h] = z[h] * z[h]; }
#pragma unroll
    for (int o = 32; o > 0; o >>= 1) {
#pragma unroll
      for (int h = 0; h < 6; ++h) {
        sm[h] += __shfl_down(sm[h], o);
        sq[h] += __shfl_down(sq[h], o);
      }
    }
    if (lane == 0) {
#pragma unroll
      for (int h = 0; h < 6; ++h) { part[wvi][h] = sm[h]; part[wvi][6 + h] = sq[h]; }
    }
    __syncthreads();
    if (b < 6) {
      float msum = part[0][b] + part[1][b] + part[2][b] + part[3][b];
      float qsum = part[0][6 + b] + part[1][6 + b] + part[2][6 + b] + part[3][6 + b];
      float m = msum * (1.f / 256.f);
      float var = qsum * (1.f / 256.f) - m * m;
      stats[b] = m;
      stats[6 + b] = rsqrtf(var + EPS);
    }
    __syncthreads();
  }

  float yr[6];
  float a3 = q3[0];
#pragma unroll
  for (int h = 0; h < 6; ++h) {
    yr[h] = (z[h] - stats[h]) * stats[6 + h] * g3[h] + e3[h];
    a3 = fmaf(yr[h], p3[h], a3);
  }
  out[(size_t)b * NOUT + 2336] = tanhf(a3) * r3[0] + s3[0];
  __syncthreads();   // stats[] about to be reused

  // ---- final head ----
  float zf[12];
#pragma unroll
  for (int j = 0; j < 12; ++j) {
    float a = fb[j];
#pragma unroll
    for (int h = 0; h < 6; ++h) a = fmaf(yr[h], fw[j * 6 + h], a);
    zf[j] = tanhf(a);
  }
  {
    float sm[12], sq[12];
#pragma unroll
    for (int j = 0; j < 12; ++j) { sm[j] = zf[j]; sq[j] = zf[j] * zf[j]; }
#pragma unroll
    for (int o = 32; o > 0; o >>= 1) {
#pragma unroll
      for (int j = 0; j < 12; ++j) {
        sm[j] += __shfl_down(sm[j], o);
        sq[j] += __shfl_down(sq[j], o);
      }
    }
    if (lane == 0) {
#pragma unroll
      for (int j = 0; j < 12; ++j) { part[wvi][j] = sm[j]; part[wvi][12 + j] = sq[j]; }
    }
    __syncthreads();
    if (b < 12) {
      float msum = part[0][b] + part[1][b] + part[2][b] + part[3][b];
      float qsum = part[0][12 + b] + part[1][12 + b] + part[2][12 + b] + part[3][12 + b];
      float m = msum * (1.f / 256.f);
      float var = qsum * (1.f / 256.f) - m * m;
      stats[b] = m;
      stats[12 + b] = rsqrtf(var + EPS);
    }
    __syncthreads();
  }
  float a = pb[0];
#pragma unroll
  for (int j = 0; j < 12; ++j) {
    float of = (zf[j] - stats[j]) * stats[12 + j] * fg[j] + fe[j];
    a = fmaf(of, pw[j], a);
  }
  out[(size_t)b * NOUT + 2337] = tanhf(a) * rw[0] + rb[0];
}

extern "C" void kernel_launch(void* const* d_in, const int* in_sizes, int n_in,
                              void* d_out, int out_size, void* d_ws, size_t ws_size,
                              hipStream_t stream) {
  const float* x  = (const float*)d_in[0];
  const float* gW = (const float*)d_in[1];
  const float* gb = (const float*)d_in[2];
  float* out = (float*)d_out;

  char* wsb = (char*)d_ws;
  u16* XBp = (u16*)wsb;                              // 256*3008 bf16 (packed)
  float* h0 = (float*)(wsb + 1540096);               // [20480][256]
  float* y0 = h0 + (size_t)20480 * 256;              // [12288][256]
  float* y1 = y0 + (size_t)12288 * 256;              // [1536][256]
  float* y2 = y1 + (size_t)1536 * 256;               // [192][256]

  cvt_pack_kernel<<<dim3(376), dim3(256), 0, stream>>>(x, XBp);
  gemm_leaf<<<dim3(640), dim3(256), 0, stream>>>(gW, gb, XBp, h0);

#define LV(base, yin, yout, inl, off, grid)                                           \
  level_kernel<<<dim3(grid), dim3(256), 0, stream>>>(                                 \
      yin, (const float*)d_in[base], (const float*)d_in[base + 1],                    \
      (const float*)d_in[base + 2], (const float*)d_in[base + 3],                     \
      (const float*)d_in[base + 4], (const float*)d_in[base + 5],                     \
      (const float*)d_in[base + 6], (const float*)d_in[base + 7], yout, out, inl, off)

  LV(3,  h0, y0, 10,  0,    2048);
  LV(11, y0, y1, 48,  2048, 256);
  LV(19, y1, y2, 48,  2304, 32);
#undef LV

  level3_final_kernel<<<dim3(1), dim3(256), 0, stream>>>(
      y2,
      (const float*)d_in[27], (const float*)d_in[28], (const float*)d_in[29],
      (const float*)d_in[30], (const float*)d_in[31], (const float*)d_in[32],
      (const float*)d_in[33], (const float*)d_in[34],
      (const float*)d_in[35], (const float*)d_in[36], (const float*)d_in[37],
      (const float*)d_in[38], (const float*)d_in[39], (const float*)d_in[40],
      (const float*)d_in[41], (const float*)d_in[42], out);
}

// Round 12
// 137.936 us; speedup vs baseline: 1.8288x; 1.3485x over previous
//
#include <hip/hip_runtime.h>
#include <hip/hip_bf16.h>
#include <stdint.h>

#define EPS 1e-5f
#define NOUT 2338   // 2048+256+32+1+1 output cols per batch row

typedef __bf16 bf16x8 __attribute__((ext_vector_type(8)));
typedef float f32x4 __attribute__((ext_vector_type(4)));
typedef unsigned short u16;

__device__ __forceinline__ u16 f2bf_bits(float f) {
  uint32_t u = __builtin_bit_cast(uint32_t, f);
  u += 0x7FFFu + ((u >> 16) & 1u);   // RNE
  return (u16)(u >> 16);
}

__device__ __forceinline__ uint32_t pack2(float lo, float hi) {
  return (uint32_t)f2bf_bits(lo) | ((uint32_t)f2bf_bits(hi) << 16);
}

// ---------------- kernel 0: x [256][3008] f32 -> bf16, packed in MFMA B-frag tile order
// XBp[ks][kb][m][e] : ks in [0,94), kb in [0,4), m in [0,256), e in [0,8)
__global__ __launch_bounds__(256) void cvt_pack_kernel(const float* __restrict__ x,
                                                       u16* __restrict__ xbp) {
  const int i = blockIdx.x * 256 + threadIdx.x;   // 96256 total
  const int ks = i >> 10;
  const int rem = i & 1023;
  const int kb = rem >> 8;
  const int m = rem & 255;
  const f32x4* src = (const f32x4*)(x + (size_t)m * 3008 + ks * 32 + kb * 8);
  f32x4 a = src[0], b = src[1];
  uint4 o;
  o.x = pack2(a.x, a.y);
  o.y = pack2(a.z, a.w);
  o.z = pack2(b.x, b.y);
  o.w = pack2(b.z, b.w);
  ((uint4*)xbp)[i] = o;
}

// ---------------- kernel 1: leaf GEMM — LDS-traffic-optimized, K-split 2.
// C [20480 x 256] = W[20480 x 3008] * X^T.  16x16x32 bf16 MFMA.
// Grid 640: bid>>1 = 64-row tile (n0), bid&1 = K-half (47 of 94 k-steps).
// Block 256 thr (4 waves). Wave w: rh=w>>1 (32 rows = 2 A-frags), mh=w&1 (8 m-tiles).
// Per wave per 32k-step: 8 B-frag + 4 W-frag ds_read_b128, 16 MFMA (0.75 reads/MFMA).
// kh=0 block adds gb; level0 sums the two h-partials.
__global__ __launch_bounds__(256, 3) void gemm_leaf(const float* __restrict__ W,
                                                    const float* __restrict__ gb,
                                                    const u16* __restrict__ XBp,
                                                    float* __restrict__ hout) {
  __shared__ __align__(16) u16 xl[2][8192];     // 2 x 16KB X tile [kb][m][e]
  __shared__ __align__(16) float wlds[2][2048]; // 2 x 8KB W slab [row(64)][32f] swizzled
  const int tid = threadIdx.x;
  const int w = tid >> 6;
  const int lane = tid & 63;
  const int rh = w >> 1;          // row-half 0..1 (32 rows)
  const int mh = w & 1;           // m-half 0..1
  const int lquad = lane >> 4;    // k-group 0..3
  const int lmod = lane & 15;
  const int n0 = (blockIdx.x >> 1) * 64;
  const int kh = blockIdx.x & 1;
  const int kbase = kh * 47;

  f32x4 acc[2][8];
#pragma unroll
  for (int a = 0; a < 2; ++a)
#pragma unroll
    for (int j = 0; j < 8; ++j) acc[a][j] = (f32x4){0.f, 0.f, 0.f, 0.f};

  // X stage: 16 coalesced 1KB chunks (4 per wave)
  const u16* xsrc = XBp + (size_t)(w * 4) * 512 + lane * 8;
#define STAGE_X(ks, buf)                                                                \
  {                                                                                     \
    _Pragma("unroll")                                                                   \
    for (int p = 0; p < 4; ++p) {                                                       \
      const u16* src = xsrc + (size_t)(ks) * 8192 + p * 512 * 4;                        \
      u16* dst = &xl[buf][(w * 4 + p * 4) * 512];                                       \
      (void)src; (void)dst;                                                             \
    }                                                                                   \
  }
#undef STAGE_X
  // (re-done below without the bad indexing)

  // chunk c = (w*4+p)*64 lanes of 8 u16
#define STAGE_X(ks, buf)                                                                \
  {                                                                                     \
    _Pragma("unroll")                                                                   \
    for (int p = 0; p < 4; ++p) {                                                       \
      const int c = (w * 4 + p) * 64;                                                   \
      const u16* src = XBp + (size_t)(ks) * 8192 + (size_t)(c + lane) * 8;              \
      u16* dst = &xl[buf][(size_t)c * 8];                                               \
      __builtin_amdgcn_global_load_lds((const __attribute__((address_space(1))) void*)src, \
                                       (__attribute__((address_space(3))) void*)dst,    \
                                       16, 0, 0);                                       \
    }                                                                                   \
  }

  // W stage: 8 coalesced 1KB instrs (2 per wave); instr p covers rows p*8..p*8+7.
  // LDS[row][b] = W[n0+row][ks*32f + (b ^ ((row&7)<<4))]; pre-swizzled global source.
  // lane: row-in-instr = lane>>3, byte-in-row = (lane&7)*16.
  const int wr0 = w * 2, wr1 = w * 2 + 1;
  const int lrow = lane >> 3;                      // 0..7 == row&7
  const int lswf = ((((lane & 7) * 16) ^ (lrow << 4)) >> 2);  // src float offset in slab
  const float* wsrc0 = W + (size_t)(n0 + wr0 * 8 + lrow) * 3008 + lswf;
  const float* wsrc1 = W + (size_t)(n0 + wr1 * 8 + lrow) * 3008 + lswf;
#define STAGE_W(ks, buf)                                                                \
  {                                                                                     \
    __builtin_amdgcn_global_load_lds(                                                   \
        (const __attribute__((address_space(1))) void*)(wsrc0 + (size_t)(ks) * 32),     \
        (__attribute__((address_space(3))) void*)&wlds[buf][wr0 * 256], 16, 0, 0);      \
    __builtin_amdgcn_global_load_lds(                                                   \
        (const __attribute__((address_space(1))) void*)(wsrc1 + (size_t)(ks) * 32),     \
        (__attribute__((address_space(3))) void*)&wlds[buf][wr1 * 256], 16, 0, 0);      \
  }

  STAGE_X(kbase, 0);
  STAGE_W(kbase, 0);

  const int xorv = (lmod & 7) << 4;
  for (int s = 0; s < 47; ++s) {
    const int buf = s & 1;
    __syncthreads();   // drains stage(s)
    if (s < 46) {
      STAGE_X(kbase + s + 1, buf ^ 1);
      STAGE_W(kbase + s + 1, buf ^ 1);
    }
    __builtin_amdgcn_sched_barrier(0);   // stage issues before compute

    const float* wbase = &wlds[buf][0];
    const u16* xb = &xl[buf][(size_t)lquad * 2048 + mh * 1024 + lmod * 8];
    union { u16 u[8]; bf16x8 v; } af[2];
#pragma unroll
    for (int a = 0; a < 2; ++a) {
      const int row = rh * 32 + a * 16 + lmod;
      const int fb = row * 32;
      const f32x4 wlo = *(const f32x4*)(wbase + fb + (((lquad * 32) ^ xorv) >> 2));
      const f32x4 whi = *(const f32x4*)(wbase + fb + (((lquad * 32 + 16) ^ xorv) >> 2));
      af[a].u[0] = f2bf_bits(wlo.x); af[a].u[1] = f2bf_bits(wlo.y);
      af[a].u[2] = f2bf_bits(wlo.z); af[a].u[3] = f2bf_bits(wlo.w);
      af[a].u[4] = f2bf_bits(whi.x); af[a].u[5] = f2bf_bits(whi.y);
      af[a].u[6] = f2bf_bits(whi.z); af[a].u[7] = f2bf_bits(whi.w);
    }
#pragma unroll
    for (int j = 0; j < 8; ++j) {
      const bf16x8 bfrag = *(const bf16x8*)(xb + j * 128);
      acc[0][j] = __builtin_amdgcn_mfma_f32_16x16x32_bf16(af[0].v, bfrag, acc[0][j], 0, 0, 0);
      acc[1][j] = __builtin_amdgcn_mfma_f32_16x16x32_bf16(af[1].v, bfrag, acc[1][j], 0, 0, 0);
    }
  }

#undef STAGE_W
#undef STAGE_X

  // store partial: hp = hout + kh*20480*256; kh==0 adds gb.
  float* hp = hout + (size_t)kh * 20480 * 256;
#pragma unroll
  for (int a = 0; a < 2; ++a) {
    const int r0 = n0 + rh * 32 + a * 16 + lquad * 4;
    float gb4[4];
#pragma unroll
    for (int r2 = 0; r2 < 4; ++r2) gb4[r2] = (kh == 0) ? gb[r0 + r2] : 0.f;
#pragma unroll
    for (int j = 0; j < 8; ++j) {
      const int col = (mh * 8 + j) * 16 + lmod;
#pragma unroll
      for (int r2 = 0; r2 < 4; ++r2) {
        hp[(size_t)(r0 + r2) * 256 + col] = acc[a][j][r2] + gb4[r2];
      }
    }
  }
}

// ---------------- level 0: one term per block, sums the two K-half partials
__global__ __launch_bounds__(256) void level0_kernel(
    const float* __restrict__ yinA, const float* __restrict__ yinB,
    const float* __restrict__ w,
    const float* __restrict__ bia, const float* __restrict__ gam,
    const float* __restrict__ bet, const float* __restrict__ p,
    const float* __restrict__ q, const float* __restrict__ r,
    const float* __restrict__ s, float* __restrict__ yout,
    float* __restrict__ out, int inl, int off) {
  const int t = blockIdx.x;
  const int b = threadIdx.x;
  __shared__ float wls[6 * 10];
  __shared__ float part[4][12];
  __shared__ float stats[12];
  const float* wt = w + (size_t)t * 6 * inl;
  for (int i = b; i < 6 * inl; i += 256) wls[i] = wt[i];
  __syncthreads();

  float z[6];
#pragma unroll
  for (int h = 0; h < 6; ++h) z[h] = bia[t * 6 + h];
  const float* ypA = yinA + (size_t)t * inl * 256 + b;
  const float* ypB = yinB + (size_t)t * inl * 256 + b;
  for (int i = 0; i < inl; ++i) {
    float v = ypA[(size_t)i * 256] + ypB[(size_t)i * 256];
#pragma unroll
    for (int h = 0; h < 6; ++h) z[h] = fmaf(v, wls[h * inl + i], z[h]);
  }
#pragma unroll
  for (int h = 0; h < 6; ++h) z[h] = tanhf(z[h]);

  float sm[6], sq[6];
#pragma unroll
  for (int h = 0; h < 6; ++h) { sm[h] = z[h]; sq[h] = z[h] * z[h]; }
#pragma unroll
  for (int o = 32; o > 0; o >>= 1) {
#pragma unroll
    for (int h = 0; h < 6; ++h) {
      sm[h] += __shfl_down(sm[h], o);
      sq[h] += __shfl_down(sq[h], o);
    }
  }
  const int lane = b & 63, wvi = b >> 6;
  if (lane == 0) {
#pragma unroll
    for (int h = 0; h < 6; ++h) { part[wvi][h] = sm[h]; part[wvi][6 + h] = sq[h]; }
  }
  __syncthreads();
  if (b < 6) {
    float msum = part[0][b] + part[1][b] + part[2][b] + part[3][b];
    float qsum = part[0][6 + b] + part[1][6 + b] + part[2][6 + b] + part[3][6 + b];
    float m = msum * (1.f / 256.f);
    float var = qsum * (1.f / 256.f) - m * m;
    stats[b] = m;
    stats[6 + b] = rsqrtf(var + EPS);
  }
  __syncthreads();

  float a = q[t];
#pragma unroll
  for (int h = 0; h < 6; ++h) {
    float yy = (z[h] - stats[h]) * stats[6 + h] * gam[t * 6 + h] + bet[t * 6 + h];
    yout[((size_t)t * 6 + h) * 256 + b] = yy;
    a = fmaf(yy, p[t * 6 + h], a);
  }
  out[(size_t)b * NOUT + off + t] = tanhf(a) * r[t] + s[t];
}

// ---------------- levels 1..2: one term per block
__global__ __launch_bounds__(256) void level_kernel(
    const float* __restrict__ yin, const float* __restrict__ w,
    const float* __restrict__ bia, const float* __restrict__ gam,
    const float* __restrict__ bet, const float* __restrict__ p,
    const float* __restrict__ q, const float* __restrict__ r,
    const float* __restrict__ s, float* __restrict__ yout,
    float* __restrict__ out, int inl, int off) {
  const int t = blockIdx.x;
  const int b = threadIdx.x;
  __shared__ float wls[6 * 48];
  __shared__ float part[4][12];
  __shared__ float stats[12];
  const float* wt = w + (size_t)t * 6 * inl;
  for (int i = b; i < 6 * inl; i += 256) wls[i] = wt[i];
  __syncthreads();

  float z[6];
#pragma unroll
  for (int h = 0; h < 6; ++h) z[h] = bia[t * 6 + h];
  const float* yp = yin + (size_t)t * inl * 256 + b;
  for (int i = 0; i < inl; ++i) {
    float v = yp[(size_t)i * 256];
#pragma unroll
    for (int h = 0; h < 6; ++h) z[h] = fmaf(v, wls[h * inl + i], z[h]);
  }
#pragma unroll
  for (int h = 0; h < 6; ++h) z[h] = tanhf(z[h]);

  float sm[6], sq[6];
#pragma unroll
  for (int h = 0; h < 6; ++h) { sm[h] = z[h]; sq[h] = z[h] * z[h]; }
#pragma unroll
  for (int o = 32; o > 0; o >>= 1) {
#pragma unroll
    for (int h = 0; h < 6; ++h) {
      sm[h] += __shfl_down(sm[h], o);
      sq[h] += __shfl_down(sq[h], o);
    }
  }
  const int lane = b & 63, wvi = b >> 6;
  if (lane == 0) {
#pragma unroll
    for (int h = 0; h < 6; ++h) { part[wvi][h] = sm[h]; part[wvi][6 + h] = sq[h]; }
  }
  __syncthreads();
  if (b < 6) {
    float msum = part[0][b] + part[1][b] + part[2][b] + part[3][b];
    float qsum = part[0][6 + b] + part[1][6 + b] + part[2][6 + b] + part[3][6 + b];
    float m = msum * (1.f / 256.f);
    float var = qsum * (1.f / 256.f) - m * m;
    stats[b] = m;
    stats[6 + b] = rsqrtf(var + EPS);
  }
  __syncthreads();

  float a = q[t];
#pragma unroll
  for (int h = 0; h < 6; ++h) {
    float yy = (z[h] - stats[h]) * stats[6 + h] * gam[t * 6 + h] + bet[t * 6 + h];
    yout[((size_t)t * 6 + h) * 256 + b] = yy;
    a = fmaf(yy, p[t * 6 + h], a);
  }
  out[(size_t)b * NOUT + off + t] = tanhf(a) * r[t] + s[t];
}

// ---------------- merged level-3 (inl=192, 1 term) + final head; single block
__global__ __launch_bounds__(256) void level3_final_kernel(
    const float* __restrict__ y2,
    const float* __restrict__ w3, const float* __restrict__ b3,
    const float* __restrict__ g3, const float* __restrict__ e3,
    const float* __restrict__ p3, const float* __restrict__ q3,
    const float* __restrict__ r3, const float* __restrict__ s3,
    const float* __restrict__ fw, const float* __restrict__ fb,
    const float* __restrict__ fg, const float* __restrict__ fe,
    const float* __restrict__ pw, const float* __restrict__ pb,
    const float* __restrict__ rw, const float* __restrict__ rb,
    float* __restrict__ out) {
  const int b = threadIdx.x;
  __shared__ float wls[6 * 192];
  __shared__ float part[4][24];
  __shared__ float stats[24];
  for (int i = b; i < 6 * 192; i += 256) wls[i] = w3[i];
  __syncthreads();

  float z[6];
#pragma unroll
  for (int h = 0; h < 6; ++h) z[h] = b3[h];
  const float* yp = y2 + b;
  for (int i = 0; i < 192; ++i) {
    float v = yp[(size_t)i * 256];
#pragma unroll
    for (int h = 0; h < 6; ++h) z[h] = fmaf(v, wls[h * 192 + i], z[h]);
  }
#pragma unroll
  for (int h = 0; h < 6; ++h) z[h] = tanhf(z[h]);

  const int lane = b & 63, wvi = b >> 6;
  {
    float sm[6], sq[6];
#pragma unroll
    for (int h = 0; h < 6; ++h) { sm[h] = z[h]; sq[h] = z[h] * z[h]; }
#pragma unroll
    for (int o = 32; o > 0; o >>= 1) {
#pragma unroll
      for (int h = 0; h < 6; ++h) {
        sm[h] += __shfl_down(sm[h], o);
        sq[h] += __shfl_down(sq[h], o);
      }
    }
    if (lane == 0) {
#pragma unroll
      for (int h = 0; h < 6; ++h) { part[wvi][h] = sm[h]; part[wvi][6 + h] = sq[h]; }
    }
    __syncthreads();
    if (b < 6) {
      float msum = part[0][b] + part[1][b] + part[2][b] + part[3][b];
      float qsum = part[0][6 + b] + part[1][6 + b] + part[2][6 + b] + part[3][6 + b];
      float m = msum * (1.f / 256.f);
      float var = qsum * (1.f / 256.f) - m * m;
      stats[b] = m;
      stats[6 + b] = rsqrtf(var + EPS);
    }
    __syncthreads();
  }

  float yr[6];
  float a3 = q3[0];
#pragma unroll
  for (int h = 0; h < 6; ++h) {
    yr[h] = (z[h] - stats[h]) * stats[6 + h] * g3[h] + e3[h];
    a3 = fmaf(yr[h], p3[h], a3);
  }
  out[(size_t)b * NOUT + 2336] = tanhf(a3) * r3[0] + s3[0];
  __syncthreads();

  float zf[12];
#pragma unroll
  for (int j = 0; j < 12; ++j) {
    float a = fb[j];
#pragma unroll
    for (int h = 0; h < 6; ++h) a = fmaf(yr[h], fw[j * 6 + h], a);
    zf[j] = tanhf(a);
  }
  {
    float sm[12], sq[12];
#pragma unroll
    for (int j = 0; j < 12; ++j) { sm[j] = zf[j]; sq[j] = zf[j] * zf[j]; }
#pragma unroll
    for (int o = 32; o > 0; o >>= 1) {
#pragma unroll
      for (int j = 0; j < 12; ++j) {
        sm[j] += __shfl_down(sm[j], o);
        sq[j] += __shfl_down(sq[j], o);
      }
    }
    if (lane == 0) {
#pragma unroll
      for (int j = 0; j < 12; ++j) { part[wvi][j] = sm[j]; part[wvi][12 + j] = sq[j]; }
    }
    __syncthreads();
    if (b < 12) {
      float msum = part[0][b] + part[1][b] + part[2][b] + part[3][b];
      float qsum = part[0][12 + b] + part[1][12 + b] + part[2][12 + b] + part[3][12 + b];
      float m = msum * (1.f / 256.f);
      float var = qsum * (1.f / 256.f) - m * m;
      stats[b] = m;
      stats[12 + b] = rsqrtf(var + EPS);
    }
    __syncthreads();
  }
  float a = pb[0];
#pragma unroll
  for (int j = 0; j < 12; ++j) {
    float of = (zf[j] - stats[j]) * stats[12 + j] * fg[j] + fe[j];
    a = fmaf(of, pw[j], a);
  }
  out[(size_t)b * NOUT + 2337] = tanhf(a) * rw[0] + rb[0];
}

extern "C" void kernel_launch(void* const* d_in, const int* in_sizes, int n_in,
                              void* d_out, int out_size, void* d_ws, size_t ws_size,
                              hipStream_t stream) {
  const float* x  = (const float*)d_in[0];
  const float* gW = (const float*)d_in[1];
  const float* gb = (const float*)d_in[2];
  float* out = (float*)d_out;

  char* wsb = (char*)d_ws;
  u16* XBp = (u16*)wsb;                              // 256*3008 bf16 (packed) = 1.54MB
  float* h0 = (float*)(wsb + 1540096);               // 2 x [20480][256] K-half partials
  float* y0 = h0 + (size_t)2 * 20480 * 256;          // [12288][256]
  float* y1 = y0 + (size_t)12288 * 256;              // [1536][256]
  float* y2 = y1 + (size_t)1536 * 256;               // [192][256]

  cvt_pack_kernel<<<dim3(376), dim3(256), 0, stream>>>(x, XBp);
  gemm_leaf<<<dim3(640), dim3(256), 0, stream>>>(gW, gb, XBp, h0);

  level0_kernel<<<dim3(2048), dim3(256), 0, stream>>>(
      h0, h0 + (size_t)20480 * 256,
      (const float*)d_in[3], (const float*)d_in[4], (const float*)d_in[5],
      (const float*)d_in[6], (const float*)d_in[7], (const float*)d_in[8],
      (const float*)d_in[9], (const float*)d_in[10], y0, out, 10, 0);

#define LV(base, yin, yout, inl, off, grid)                                           \
  level_kernel<<<dim3(grid), dim3(256), 0, stream>>>(                                 \
      yin, (const float*)d_in[base], (const float*)d_in[base + 1],                    \
      (const float*)d_in[base + 2], (const float*)d_in[base + 3],                     \
      (const float*)d_in[base + 4], (const float*)d_in[base + 5],                     \
      (const float*)d_in[base + 6], (const float*)d_in[base + 7], yout, out, inl, off)

  LV(11, y0, y1, 48,  2048, 256);
  LV(19, y1, y2, 48,  2304, 32);
#undef LV

  level3_final_kernel<<<dim3(1), dim3(256), 0, stream>>>(
      y2,
      (const float*)d_in[27], (const float*)d_in[28], (const float*)d_in[29],
      (const float*)d_in[30], (const float*)d_in[31], (const float*)d_in[32],
      (const float*)d_in[33], (const float*)d_in[34],
      (const float*)d_in[35], (const float*)d_in[36], (const float*)d_in[37],
      (const float*)d_in[38], (const float*)d_in[39], (const float*)d_in[40],
      (const float*)d_in[41], (const float*)d_in[42], out);
}